// Round 4
// baseline (10296.592 us; speedup 1.0000x reference)
//
#include <hip/hip_runtime.h>
#include <math.h>

#define SEQ    2048
#define BATCH  32
#define IN_DIM 512
#define HID    512
#define GATES  (4*HID)   // 2048

typedef __attribute__((ext_vector_type(4))) float f32x4;
typedef __attribute__((ext_vector_type(2))) float f32x2;

// ---------------------------------------------------------------------------
// x_proj GEMM:  xp[m][n] = sum_k x[m][k]*Wih[n][k] + bih[n] + bhh[n]
// ---------------------------------------------------------------------------
__global__ __launch_bounds__(256) void xproj_kernel(
    const float* __restrict__ x,     // [M][512]
    const float* __restrict__ Wih,   // [2048][512]
    const float* __restrict__ bih,
    const float* __restrict__ bhh,
    float* __restrict__ xp,          // [M][2048]
    int M)
{
    __shared__ float As[16][132];
    __shared__ float Bs[16][132];
    const int tid = threadIdx.x;
    const int nb = blockIdx.x & 15;
    const int mb = blockIdx.x >> 4;
    const int m0 = mb * 128, n0 = nb * 128;
    const int tx = tid & 15, ty = tid >> 4;

    float acc[8][8];
#pragma unroll
    for (int i = 0; i < 8; ++i)
#pragma unroll
        for (int j = 0; j < 8; ++j) acc[i][j] = 0.f;

    for (int kc = 0; kc < 512; kc += 16) {
#pragma unroll
        for (int h = 0; h < 2; ++h) {
            int f4 = tid + 256 * h;
            int r = f4 >> 2, u = f4 & 3;
            float4 va = *(const float4*)(x + (size_t)(m0 + r) * 512 + kc + 4 * u);
            As[4*u+0][r] = va.x; As[4*u+1][r] = va.y;
            As[4*u+2][r] = va.z; As[4*u+3][r] = va.w;
            float4 vb = *(const float4*)(Wih + (size_t)(n0 + r) * 512 + kc + 4 * u);
            Bs[4*u+0][r] = vb.x; Bs[4*u+1][r] = vb.y;
            Bs[4*u+2][r] = vb.z; Bs[4*u+3][r] = vb.w;
        }
        __syncthreads();
#pragma unroll
        for (int kk = 0; kk < 16; ++kk) {
            float4 a0 = *(const float4*)&As[kk][tx * 8];
            float4 a1 = *(const float4*)&As[kk][tx * 8 + 4];
            float4 b0 = *(const float4*)&Bs[kk][ty * 8];
            float4 b1 = *(const float4*)&Bs[kk][ty * 8 + 4];
            float av[8] = {a0.x,a0.y,a0.z,a0.w,a1.x,a1.y,a1.z,a1.w};
            float bv[8] = {b0.x,b0.y,b0.z,b0.w,b1.x,b1.y,b1.z,b1.w};
#pragma unroll
            for (int i = 0; i < 8; ++i)
#pragma unroll
                for (int j = 0; j < 8; ++j) acc[i][j] += av[i] * bv[j];
        }
        __syncthreads();
    }

    float bias[8];
#pragma unroll
    for (int j = 0; j < 8; ++j) {
        int n = n0 + ty * 8 + j;
        bias[j] = bih[n] + bhh[n];
    }
#pragma unroll
    for (int i = 0; i < 8; ++i) {
        size_t base = (size_t)(m0 + tx * 8 + i) * GATES + n0 + ty * 8;
        float4 v0 = make_float4(acc[i][0]+bias[0], acc[i][1]+bias[1],
                                acc[i][2]+bias[2], acc[i][3]+bias[3]);
        float4 v1 = make_float4(acc[i][4]+bias[4], acc[i][5]+bias[5],
                                acc[i][6]+bias[6], acc[i][7]+bias[7]);
        *(float4*)(xp + base)     = v0;
        *(float4*)(xp + base + 4) = v1;
    }
}

// ---------------------------------------------------------------------------
// Scan. 8 independent groups (4 batches) x 32 WGs (16 hid each).
// h exchange: 8B granules {h, tagf} in LLC (sc0 sc1). Granule index
// G = 4*slot + batch_j, slot(k) = 16*(k&31) + (k>>5)  (k = hid).
// Consumer thread stages slots {tid, tid+256}: 8 coalesced dwordx2 loads,
// retry until all tags == (float)t bitwise. One syncthreads per step
// (LDS double-buffered). Wave hw owns hid {4hw+rr}, all 4 gates, 4 batches:
// after 4-stage butterfly + 3 shuffles, tail lanes (lane&12)==0 compute the
// cell and publish {h,tag=t+1} with a single atomic 8B store. Safety: tag
// equality + (stage -> sync -> publish) order makes 2-parity reuse race-free.
// ---------------------------------------------------------------------------
__global__ __launch_bounds__(256, 1)
__attribute__((amdgpu_waves_per_eu(1, 1)))
void lstm_coop(
    const float* __restrict__ Whh,   // [2048][512]
    const float* __restrict__ xp,    // [nsteps][32][2048]
    float* __restrict__ hx,          // [2][8][2048 granules][2] floats
    float* __restrict__ cbuf,        // [32][512]
    float* __restrict__ out_hs,      // [2048][32][512]
    int t0, int nsteps)
{
    const int w    = blockIdx.x;
    const int g    = w >> 5;         // batch-quad group
    const int sl   = w & 31;         // hid slice [16sl, 16sl+16)
    const int tid  = threadIdx.x;
    const int hw   = tid >> 6;       // wave: hid {4hw..4hw+3} within slice
    const int lane = tid & 63;
    const int rr   = (lane >> 4) & 3;
    const int kg   = lane & 15;      // k-chunk [32kg, 32kg+32)

    __shared__ f32x4 h4[2][512];

    // W rows: 4 gates x hid(16sl+4hw+rr), k-chunk 32 -> 128 floats in VGPRs
    float wreg[4][32];
#pragma unroll
    for (int gi = 0; gi < 4; ++gi) {
        const float* wr = Whh + (size_t)(512*gi + 16*sl + 4*hw + rr) * 512 + 32*kg;
#pragma unroll
        for (int q = 0; q < 8; ++q) {
            float4 v = *(const float4*)(wr + 4*q);
            wreg[gi][4*q+0] = v.x; wreg[gi][4*q+1] = v.y;
            wreg[gi][4*q+2] = v.z; wreg[gi][4*q+3] = v.w;
        }
    }

    const bool is_tail = ((lane & 12) == 0);   // kg < 4
    const int  jb      = lane & 3;
    const int  hid_gl  = 16*sl + 4*hw + rr;
    const int  b_gl    = 4*g + jb;
    const int  slot_p  = 16*(hid_gl & 31) + (hid_gl >> 5);

    float c_reg = 0.f;
    if (is_tail) c_reg = cbuf[(size_t)b_gl * HID + hid_gl];

    for (int t = t0; t < t0 + nsteps; ++t) {
        const int p = t & 1;
        // xp prefetch for this lane's post-butterfly output (gate=kg>>2, b=kg&3)
        const int xrow = 512*(kg >> 2) + 16*sl + 4*hw + rr;
        const int xb   = 4*g + (kg & 3);
        float xpv = xp[(size_t)(t - t0) * (BATCH * GATES)
                       + (size_t)xb * GATES + xrow];

        // ---- poll + load 8 tagged granules (slots tid, tid+256)
        const float* rb = hx + ((size_t)p * 8 + g) * 4096;
        const float* p0 = rb + 8 * tid;
        const float* p1 = rb + 8 * tid + 2048;
        const unsigned tu = __float_as_uint((float)t);
        f32x2 a0, a1, a2, a3, b0, b1, b2, b3;
        while (true) {
            asm volatile(
                "global_load_dwordx2 %0, %8, off sc0 sc1\n\t"
                "global_load_dwordx2 %1, %8, off offset:8 sc0 sc1\n\t"
                "global_load_dwordx2 %2, %8, off offset:16 sc0 sc1\n\t"
                "global_load_dwordx2 %3, %8, off offset:24 sc0 sc1\n\t"
                "global_load_dwordx2 %4, %9, off sc0 sc1\n\t"
                "global_load_dwordx2 %5, %9, off offset:8 sc0 sc1\n\t"
                "global_load_dwordx2 %6, %9, off offset:16 sc0 sc1\n\t"
                "global_load_dwordx2 %7, %9, off offset:24 sc0 sc1\n\t"
                "s_waitcnt vmcnt(0)"
                : "=&v"(a0), "=&v"(a1), "=&v"(a2), "=&v"(a3),
                  "=&v"(b0), "=&v"(b1), "=&v"(b2), "=&v"(b3)
                : "v"(p0), "v"(p1)
                : "memory");
            if (__float_as_uint(a0[1]) == tu && __float_as_uint(a1[1]) == tu &&
                __float_as_uint(a2[1]) == tu && __float_as_uint(a3[1]) == tu &&
                __float_as_uint(b0[1]) == tu && __float_as_uint(b1[1]) == tu &&
                __float_as_uint(b2[1]) == tu && __float_as_uint(b3[1]) == tu)
                break;
            __builtin_amdgcn_s_sleep(1);
        }
        {
            f32x4 v0 = {a0[0], a1[0], a2[0], a3[0]};
            f32x4 v1 = {b0[0], b1[0], b2[0], b3[0]};
            h4[p][tid]       = v0;
            h4[p][tid + 256] = v1;
        }
        __syncthreads();

        // ---- dot: 32 x (b128 broadcast read + 16 FMA)
        float acc[16];
#pragma unroll
        for (int m = 0; m < 16; ++m) acc[m] = 0.f;
#pragma unroll
        for (int s = 0; s < 32; ++s) {
            f32x4 hv = h4[p][16*s + kg];
#pragma unroll
            for (int gi = 0; gi < 4; ++gi) {
                acc[4*gi+0] += wreg[gi][s] * hv[0];
                acc[4*gi+1] += wreg[gi][s] * hv[1];
                acc[4*gi+2] += wreg[gi][s] * hv[2];
                acc[4*gi+3] += wreg[gi][s] * hv[3];
            }
        }

        // ---- 4-stage index-descending butterfly over kg -> lane kg has acc[kg]
        {
            int sel = (kg >> 3) & 1;
#pragma unroll
            for (int m = 0; m < 8; ++m) {
                float mine = sel ? acc[m+8] : acc[m];
                float send = sel ? acc[m]   : acc[m+8];
                acc[m] = mine + __shfl_xor(send, 8, 64);
            }
        }
        {
            int sel = (kg >> 2) & 1;
#pragma unroll
            for (int m = 0; m < 4; ++m) {
                float mine = sel ? acc[m+4] : acc[m];
                float send = sel ? acc[m]   : acc[m+4];
                acc[m] = mine + __shfl_xor(send, 4, 64);
            }
        }
        {
            int sel = (kg >> 1) & 1;
#pragma unroll
            for (int m = 0; m < 2; ++m) {
                float mine = sel ? acc[m+2] : acc[m];
                float send = sel ? acc[m]   : acc[m+2];
                acc[m] = mine + __shfl_xor(send, 2, 64);
            }
        }
        {
            int sel = kg & 1;
            float mine = sel ? acc[1] : acc[0];
            float send = sel ? acc[0] : acc[1];
            acc[0] = mine + __shfl_xor(send, 1, 64);
        }

        // lane (rr,kg) now owns gate kg>>2, batch kg&3, hid 4hw+rr
        float gval = acc[0] + xpv;
        // gather the other 3 gates into tail lanes (kg<4, gate0 = own)
        float fv2 = __shfl(gval, (lane & 48) + 4  + jb);
        float gv2 = __shfl(gval, (lane & 48) + 8  + jb);
        float ov2 = __shfl(gval, (lane & 48) + 12 + jb);

        if (is_tail) {
            float iv = 1.f / (1.f + expf(-gval));
            float fv = 1.f / (1.f + expf(-fv2));
            float gv = tanhf(gv2);
            float ov = 1.f / (1.f + expf(-ov2));
            float cn = fv * c_reg + iv * gv;
            float hn = ov * tanhf(cn);
            c_reg = cn;
            f32x2 pkt;
            pkt[0] = hn;
            pkt[1] = (float)(t + 1);
            float* wp = hx + ((size_t)((t + 1) & 1) * 8 + g) * 4096
                        + 8 * slot_p + 2 * jb;
            asm volatile("global_store_dwordx2 %0, %1, off sc0 sc1"
                         :: "v"(wp), "v"(pkt) : "memory");
            // off-critical-path output store
            out_hs[(size_t)t * (BATCH * HID) + (size_t)b_gl * HID + hid_gl] = hn;
        }
    }

    if (is_tail) cbuf[(size_t)b_gl * HID + hid_gl] = c_reg;
}

// ---------------------------------------------------------------------------
__global__ void init_kernel(const float* __restrict__ h0,
                            const float* __restrict__ c0,
                            float* __restrict__ hx,
                            float* __restrict__ cbuf)
{
    int idx = blockIdx.x * 256 + threadIdx.x;
    if (idx < 16384) {
        int g = idx >> 11, G = idx & 2047;
        int slot = G >> 2, c = G & 3;
        int k = 32 * (slot & 15) + (slot >> 4);
        int b = 4 * g + c;
        // parity 0: h0 with tag 0
        hx[(size_t)g * 4096 + 2*G]     = h0[(size_t)b * HID + k];
        hx[(size_t)g * 4096 + 2*G + 1] = 0.0f;
        // parity 1: invalid tag (NaN bits -> never equals any (float)t)
        hx[(size_t)32768 + (size_t)g * 4096 + 2*G]     = 0.0f;
        hx[(size_t)32768 + (size_t)g * 4096 + 2*G + 1] = __uint_as_float(0xFFFFFFFFu);
        cbuf[idx] = c0[idx];
    }
}

__global__ void tail_kernel(const float* __restrict__ hx,   // parity 0 = h_SEQ
                            const float* __restrict__ cbuf,
                            float* __restrict__ out)
{
    int idx = blockIdx.x * 256 + threadIdx.x;
    if (idx < BATCH * HID) {
        int b = idx >> 9, k = idx & 511;
        int g = b >> 2, c = b & 3;
        int slot = 16 * (k & 31) + (k >> 5);
        int G = 4 * slot + c;
        out[(size_t)SEQ * BATCH * HID + idx] = hx[(size_t)g * 4096 + 2*G];
        out[(size_t)SEQ * BATCH * HID + BATCH * HID + idx] = cbuf[idx];
    }
}

// ---------------------------------------------------------------------------
extern "C" void kernel_launch(void* const* d_in, const int* in_sizes, int n_in,
                              void* d_out, int out_size, void* d_ws, size_t ws_size,
                              hipStream_t stream)
{
    const float* x   = (const float*)d_in[0];
    const float* h0  = (const float*)d_in[1];
    const float* c0  = (const float*)d_in[2];
    const float* Wih = (const float*)d_in[3];
    const float* Whh = (const float*)d_in[4];
    const float* bih = (const float*)d_in[5];
    const float* bhh = (const float*)d_in[6];
    float* out = (float*)d_out;

    float* hx   = (float*)d_ws;              // 65536 floats (2x8x2048x2)
    float* cbuf = hx + 65536;                // 16384 floats
    float* xp   = cbuf + 16384;
    size_t used_floats = 65536 + 16384;
    size_t avail = (ws_size / 4 > used_floats) ? (ws_size / 4 - used_floats) : 0;
    int chunk = (int)(avail / (size_t)(BATCH * GATES));
    if (chunk > SEQ) chunk = SEQ;
    chunk &= ~3;
    if (chunk < 4) chunk = 4;

    hipLaunchKernelGGL(init_kernel, dim3(64), dim3(256), 0, stream,
                       h0, c0, hx, cbuf);

    for (int t0 = 0; t0 < SEQ; t0 += chunk) {
        int n = SEQ - t0; if (n > chunk) n = chunk;
        int M = n * BATCH;
        hipLaunchKernelGGL(xproj_kernel, dim3(16 * (M / 128)), dim3(256), 0, stream,
                           x + (size_t)t0 * BATCH * IN_DIM, Wih, bih, bhh, xp, M);

        const float* xp_c = xp;
        int t0_arg = t0, n_arg = n;
        void* args[] = { (void*)&Whh, (void*)&xp_c, (void*)&hx, (void*)&cbuf,
                         (void*)&out, (void*)&t0_arg, (void*)&n_arg };
        hipLaunchCooperativeKernel((void*)lstm_coop, dim3(256), dim3(256),
                                   args, 0, stream);
    }

    hipLaunchKernelGGL(tail_kernel, dim3(64), dim3(256), 0, stream,
                       hx, cbuf, out);
}

// Round 5
// 9367.986 us; speedup vs baseline: 1.0991x; 1.0991x over previous
//
#include <hip/hip_runtime.h>
#include <math.h>

#define SEQ    2048
#define BATCH  32
#define IN_DIM 512
#define HID    512
#define GATES  (4*HID)   // 2048

typedef __attribute__((ext_vector_type(4))) float f32x4;
typedef __attribute__((ext_vector_type(2))) float f32x2;

__device__ inline float fsigmoid(float x) {
    return 1.f / (1.f + __expf(-x));
}
__device__ inline float ftanh(float x) {
    return 1.f - 2.f / (1.f + __expf(2.f * x));
}

// ---------------------------------------------------------------------------
// x_proj GEMM:  xp[m][n] = sum_k x[m][k]*Wih[n][k] + bih[n] + bhh[n]
// ---------------------------------------------------------------------------
__global__ __launch_bounds__(256) void xproj_kernel(
    const float* __restrict__ x,     // [M][512]
    const float* __restrict__ Wih,   // [2048][512]
    const float* __restrict__ bih,
    const float* __restrict__ bhh,
    float* __restrict__ xp,          // [M][2048]
    int M)
{
    __shared__ float As[16][132];
    __shared__ float Bs[16][132];
    const int tid = threadIdx.x;
    const int nb = blockIdx.x & 15;
    const int mb = blockIdx.x >> 4;
    const int m0 = mb * 128, n0 = nb * 128;
    const int tx = tid & 15, ty = tid >> 4;

    float acc[8][8];
#pragma unroll
    for (int i = 0; i < 8; ++i)
#pragma unroll
        for (int j = 0; j < 8; ++j) acc[i][j] = 0.f;

    for (int kc = 0; kc < 512; kc += 16) {
#pragma unroll
        for (int h = 0; h < 2; ++h) {
            int f4 = tid + 256 * h;
            int r = f4 >> 2, u = f4 & 3;
            float4 va = *(const float4*)(x + (size_t)(m0 + r) * 512 + kc + 4 * u);
            As[4*u+0][r] = va.x; As[4*u+1][r] = va.y;
            As[4*u+2][r] = va.z; As[4*u+3][r] = va.w;
            float4 vb = *(const float4*)(Wih + (size_t)(n0 + r) * 512 + kc + 4 * u);
            Bs[4*u+0][r] = vb.x; Bs[4*u+1][r] = vb.y;
            Bs[4*u+2][r] = vb.z; Bs[4*u+3][r] = vb.w;
        }
        __syncthreads();
#pragma unroll
        for (int kk = 0; kk < 16; ++kk) {
            float4 a0 = *(const float4*)&As[kk][tx * 8];
            float4 a1 = *(const float4*)&As[kk][tx * 8 + 4];
            float4 b0 = *(const float4*)&Bs[kk][ty * 8];
            float4 b1 = *(const float4*)&Bs[kk][ty * 8 + 4];
            float av[8] = {a0.x,a0.y,a0.z,a0.w,a1.x,a1.y,a1.z,a1.w};
            float bv[8] = {b0.x,b0.y,b0.z,b0.w,b1.x,b1.y,b1.z,b1.w};
#pragma unroll
            for (int i = 0; i < 8; ++i)
#pragma unroll
                for (int j = 0; j < 8; ++j) acc[i][j] += av[i] * bv[j];
        }
        __syncthreads();
    }

    float bias[8];
#pragma unroll
    for (int j = 0; j < 8; ++j) {
        int n = n0 + ty * 8 + j;
        bias[j] = bih[n] + bhh[n];
    }
#pragma unroll
    for (int i = 0; i < 8; ++i) {
        size_t base = (size_t)(m0 + tx * 8 + i) * GATES + n0 + ty * 8;
        float4 v0 = make_float4(acc[i][0]+bias[0], acc[i][1]+bias[1],
                                acc[i][2]+bias[2], acc[i][3]+bias[3]);
        float4 v1 = make_float4(acc[i][4]+bias[4], acc[i][5]+bias[5],
                                acc[i][6]+bias[6], acc[i][7]+bias[7]);
        *(float4*)(xp + base)     = v0;
        *(float4*)(xp + base + 4) = v1;
    }
}

// ---------------------------------------------------------------------------
// Scan. 8 independent groups (4 batches) x 32 WGs (16 hid each).
// h exchange: 8B granules {h, tagf} in LLC (sc0 sc1), exact-equality tags.
// W slice (128 floats/thread) FORCED into VGPRs via volatile-asm loads --
// volatile results can't be rematerialized, so no per-step W re-fetch.
// ---------------------------------------------------------------------------
__global__ __launch_bounds__(256, 1)
__attribute__((amdgpu_waves_per_eu(1, 1)))
void lstm_coop(
    const float* __restrict__ Whh,   // [2048][512]
    const float* __restrict__ xp,    // [nsteps][32][2048]
    float* __restrict__ hx,          // [2][8][2048 granules][2] floats
    float* __restrict__ cbuf,        // [32][512]
    float* __restrict__ out_hs,      // [2048][32][512]
    int t0, int nsteps)
{
    const int w    = blockIdx.x;
    const int g    = w >> 5;         // batch-quad group
    const int sl   = w & 31;         // hid slice [16sl, 16sl+16)
    const int tid  = threadIdx.x;
    const int hw   = tid >> 6;       // wave: hid {4hw..4hw+3} within slice
    const int lane = tid & 63;
    const int rr   = (lane >> 4) & 3;
    const int kg   = lane & 15;      // k-chunk [32kg, 32kg+32)

    __shared__ f32x4 h4[2][512];

    // W rows: 4 gates x hid(16sl+4hw+rr), k-chunk 32 -> 32 x f32x4, pinned.
    f32x4 wv[32];
#pragma unroll
    for (int gi = 0; gi < 4; ++gi) {
        const float* wr = Whh + (size_t)(512*gi + 16*sl + 4*hw + rr) * 512 + 32*kg;
#pragma unroll
        for (int q = 0; q < 8; ++q) {
            asm volatile("global_load_dwordx4 %0, %1, off"
                         : "=v"(wv[gi*8+q]) : "v"(wr + 4*q));
        }
    }
    asm volatile("s_waitcnt vmcnt(0)" ::: "memory");

    const bool is_tail = ((lane & 12) == 0);   // kg < 4
    const int  jb      = lane & 3;
    const int  hid_gl  = 16*sl + 4*hw + rr;
    const int  b_gl    = 4*g + jb;
    const int  slot_p  = 16*(hid_gl & 31) + (hid_gl >> 5);

    float c_reg = 0.f;
    if (is_tail) c_reg = cbuf[(size_t)b_gl * HID + hid_gl];

    for (int t = t0; t < t0 + nsteps; ++t) {
        const int p = t & 1;
        // xp prefetch for this lane's post-butterfly output (gate=kg>>2, b=kg&3)
        const int xrow = 512*(kg >> 2) + 16*sl + 4*hw + rr;
        const int xb   = 4*g + (kg & 3);
        float xpv = xp[(size_t)(t - t0) * (BATCH * GATES)
                       + (size_t)xb * GATES + xrow];

        // ---- poll + load 8 tagged granules (slots tid, tid+256)
        const float* rb = hx + ((size_t)p * 8 + g) * 4096;
        const float* p0 = rb + 8 * tid;
        const float* p1 = rb + 8 * tid + 2048;
        const unsigned tu = __float_as_uint((float)t);
        f32x2 a0, a1, a2, a3, b0, b1, b2, b3;
        while (true) {
            asm volatile(
                "global_load_dwordx2 %0, %8, off sc0 sc1\n\t"
                "global_load_dwordx2 %1, %8, off offset:8 sc0 sc1\n\t"
                "global_load_dwordx2 %2, %8, off offset:16 sc0 sc1\n\t"
                "global_load_dwordx2 %3, %8, off offset:24 sc0 sc1\n\t"
                "global_load_dwordx2 %4, %9, off sc0 sc1\n\t"
                "global_load_dwordx2 %5, %9, off offset:8 sc0 sc1\n\t"
                "global_load_dwordx2 %6, %9, off offset:16 sc0 sc1\n\t"
                "global_load_dwordx2 %7, %9, off offset:24 sc0 sc1\n\t"
                "s_waitcnt vmcnt(0)"
                : "=&v"(a0), "=&v"(a1), "=&v"(a2), "=&v"(a3),
                  "=&v"(b0), "=&v"(b1), "=&v"(b2), "=&v"(b3)
                : "v"(p0), "v"(p1)
                : "memory");
            if (__float_as_uint(a0[1]) == tu && __float_as_uint(a1[1]) == tu &&
                __float_as_uint(a2[1]) == tu && __float_as_uint(a3[1]) == tu &&
                __float_as_uint(b0[1]) == tu && __float_as_uint(b1[1]) == tu &&
                __float_as_uint(b2[1]) == tu && __float_as_uint(b3[1]) == tu)
                break;
            __builtin_amdgcn_s_sleep(1);
        }
        {
            f32x4 v0 = {a0[0], a1[0], a2[0], a3[0]};
            f32x4 v1 = {b0[0], b1[0], b2[0], b3[0]};
            h4[p][tid]       = v0;
            h4[p][tid + 256] = v1;
        }
        __syncthreads();

        // ---- dot: 32 x (b128 broadcast read + 16 FMA), W from pinned VGPRs
        float acc[16];
#pragma unroll
        for (int m = 0; m < 16; ++m) acc[m] = 0.f;
#pragma unroll
        for (int s = 0; s < 32; ++s) {
            f32x4 hv = h4[p][16*s + kg];
#pragma unroll
            for (int gi = 0; gi < 4; ++gi) {
                float wt = wv[gi*8 + (s >> 2)][s & 3];
                acc[4*gi+0] += wt * hv[0];
                acc[4*gi+1] += wt * hv[1];
                acc[4*gi+2] += wt * hv[2];
                acc[4*gi+3] += wt * hv[3];
            }
        }

        // ---- 4-stage index-descending butterfly over kg -> lane kg has acc[kg]
        {
            int sel = (kg >> 3) & 1;
#pragma unroll
            for (int m = 0; m < 8; ++m) {
                float mine = sel ? acc[m+8] : acc[m];
                float send = sel ? acc[m]   : acc[m+8];
                acc[m] = mine + __shfl_xor(send, 8, 64);
            }
        }
        {
            int sel = (kg >> 2) & 1;
#pragma unroll
            for (int m = 0; m < 4; ++m) {
                float mine = sel ? acc[m+4] : acc[m];
                float send = sel ? acc[m]   : acc[m+4];
                acc[m] = mine + __shfl_xor(send, 4, 64);
            }
        }
        {
            int sel = (kg >> 1) & 1;
#pragma unroll
            for (int m = 0; m < 2; ++m) {
                float mine = sel ? acc[m+2] : acc[m];
                float send = sel ? acc[m]   : acc[m+2];
                acc[m] = mine + __shfl_xor(send, 2, 64);
            }
        }
        {
            int sel = kg & 1;
            float mine = sel ? acc[1] : acc[0];
            float send = sel ? acc[0] : acc[1];
            acc[0] = mine + __shfl_xor(send, 1, 64);
        }

        // lane (rr,kg) now owns gate kg>>2, batch kg&3, hid 4hw+rr
        float gval = acc[0] + xpv;
        // gather the other 3 gates into tail lanes (kg<4, gate0 = own)
        float fv2 = __shfl(gval, (lane & 48) + 4  + jb);
        float gv2 = __shfl(gval, (lane & 48) + 8  + jb);
        float ov2 = __shfl(gval, (lane & 48) + 12 + jb);

        if (is_tail) {
            float iv = fsigmoid(gval);
            float fv = fsigmoid(fv2);
            float gv = ftanh(gv2);
            float ov = fsigmoid(ov2);
            float cn = fv * c_reg + iv * gv;
            float hn = ov * ftanh(cn);
            c_reg = cn;
            f32x2 pkt;
            pkt[0] = hn;
            pkt[1] = (float)(t + 1);
            float* wp = hx + ((size_t)((t + 1) & 1) * 8 + g) * 4096
                        + 8 * slot_p + 2 * jb;
            asm volatile("global_store_dwordx2 %0, %1, off sc0 sc1"
                         :: "v"(wp), "v"(pkt) : "memory");
            // off-critical-path output store
            out_hs[(size_t)t * (BATCH * HID) + (size_t)b_gl * HID + hid_gl] = hn;
        }
    }

    if (is_tail) cbuf[(size_t)b_gl * HID + hid_gl] = c_reg;
}

// ---------------------------------------------------------------------------
__global__ void init_kernel(const float* __restrict__ h0,
                            const float* __restrict__ c0,
                            float* __restrict__ hx,
                            float* __restrict__ cbuf)
{
    int idx = blockIdx.x * 256 + threadIdx.x;
    if (idx < 16384) {
        int g = idx >> 11, G = idx & 2047;
        int slot = G >> 2, c = G & 3;
        int k = 32 * (slot & 15) + (slot >> 4);
        int b = 4 * g + c;
        // parity 0: h0 with tag 0
        hx[(size_t)g * 4096 + 2*G]     = h0[(size_t)b * HID + k];
        hx[(size_t)g * 4096 + 2*G + 1] = 0.0f;
        // parity 1: invalid tag (NaN bits -> never equals any (float)t)
        hx[(size_t)32768 + (size_t)g * 4096 + 2*G]     = 0.0f;
        hx[(size_t)32768 + (size_t)g * 4096 + 2*G + 1] = __uint_as_float(0xFFFFFFFFu);
        cbuf[idx] = c0[idx];
    }
}

__global__ void tail_kernel(const float* __restrict__ hx,   // parity 0 = h_SEQ
                            const float* __restrict__ cbuf,
                            float* __restrict__ out)
{
    int idx = blockIdx.x * 256 + threadIdx.x;
    if (idx < BATCH * HID) {
        int b = idx >> 9, k = idx & 511;
        int g = b >> 2, c = b & 3;
        int slot = 16 * (k & 31) + (k >> 5);
        int G = 4 * slot + c;
        out[(size_t)SEQ * BATCH * HID + idx] = hx[(size_t)g * 4096 + 2*G];
        out[(size_t)SEQ * BATCH * HID + BATCH * HID + idx] = cbuf[idx];
    }
}

// ---------------------------------------------------------------------------
extern "C" void kernel_launch(void* const* d_in, const int* in_sizes, int n_in,
                              void* d_out, int out_size, void* d_ws, size_t ws_size,
                              hipStream_t stream)
{
    const float* x   = (const float*)d_in[0];
    const float* h0  = (const float*)d_in[1];
    const float* c0  = (const float*)d_in[2];
    const float* Wih = (const float*)d_in[3];
    const float* Whh = (const float*)d_in[4];
    const float* bih = (const float*)d_in[5];
    const float* bhh = (const float*)d_in[6];
    float* out = (float*)d_out;

    float* hx   = (float*)d_ws;              // 65536 floats (2x8x2048x2)
    float* cbuf = hx + 65536;                // 16384 floats
    float* xp   = cbuf + 16384;
    size_t used_floats = 65536 + 16384;
    size_t avail = (ws_size / 4 > used_floats) ? (ws_size / 4 - used_floats) : 0;
    int chunk = (int)(avail / (size_t)(BATCH * GATES));
    if (chunk > SEQ) chunk = SEQ;
    chunk &= ~3;
    if (chunk < 4) chunk = 4;

    hipLaunchKernelGGL(init_kernel, dim3(64), dim3(256), 0, stream,
                       h0, c0, hx, cbuf);

    for (int t0 = 0; t0 < SEQ; t0 += chunk) {
        int n = SEQ - t0; if (n > chunk) n = chunk;
        int M = n * BATCH;
        hipLaunchKernelGGL(xproj_kernel, dim3(16 * (M / 128)), dim3(256), 0, stream,
                           x + (size_t)t0 * BATCH * IN_DIM, Wih, bih, bhh, xp, M);

        const float* xp_c = xp;
        int t0_arg = t0, n_arg = n;
        void* args[] = { (void*)&Whh, (void*)&xp_c, (void*)&hx, (void*)&cbuf,
                         (void*)&out, (void*)&t0_arg, (void*)&n_arg };
        hipLaunchCooperativeKernel((void*)lstm_coop, dim3(256), dim3(256),
                                   args, 0, stream);
    }

    hipLaunchKernelGGL(tail_kernel, dim3(64), dim3(256), 0, stream,
                       hx, cbuf, out);
}